// Round 5
// baseline (206.464 us; speedup 1.0000x reference)
//
#include <hip/hip_runtime.h>
#include <math.h>

#define HWSZ 4096   // 64*64
#define DIM  64
#define KCW  512
#define NROW 131072 // 32*4096
#define MT   64     // rows per block
#define PAD  68     // LDS pitch (floats) for [d][*] tiles: 68*4B=272B -> shifts banks per d, 16B-aligned
// ws float layout: [0] loss acc; [64..576) csq; [1024..1024+DIM*KCW) cwT[d][k]
#define WS_CSQ 64
#define WS_CWT 1024

// prep: zero loss, transpose codebook into ws (cwT[d][k]), and per-codeword sq-norms
__global__ void vq_prep_kernel(const float* __restrict__ cw, float* __restrict__ ws) {
    int tg = blockIdx.x * 256 + threadIdx.x;          // grid 128*256 = 32768 = DIM*KCW
    if (tg == 0) ws[0] = 0.f;
    int d = tg & (DIM - 1), k = tg >> 6;
    ws[WS_CWT + d * KCW + k] = cw[k * DIM + d];       // reads coalesced (lanes vary d)
    if (tg < KCW) {
        const float4* c4 = (const float4*)(cw + (size_t)tg * DIM);
        float s0 = 0.f, s1 = 0.f, s2 = 0.f, s3 = 0.f;
        #pragma unroll
        for (int i = 0; i < 16; ++i) {
            float4 c = c4[i];
            s0 = fmaf(c.x, c.x, s0); s1 = fmaf(c.y, c.y, s1);
            s2 = fmaf(c.z, c.z, s2); s3 = fmaf(c.w, c.w, s3);
        }
        ws[WS_CSQ + tg] = (s0 + s1) + (s2 + s3);
    }
}

// GEMM-style register-tiled distance kernel: 256 threads, 64 rows x 512 codewords per block.
// Thread (tx=t&15, ty=t>>4) owns a 4x4 (row x col) accumulator tile -> ~40 VGPRs of state,
// nothing for the allocator to spill (the R1-R4 failure mode was per-thread x[64] arrays).
__global__ __launch_bounds__(256, 4)
void vq_main_kernel(const float* __restrict__ in,
                    const float* __restrict__ cw,
                    const float* __restrict__ ws_ro,   // csq @ +64, cwT @ +1024
                    float* __restrict__ loss_acc,      // ws + 0
                    float* __restrict__ out) {
    __shared__ float xl[DIM * PAD];   // x tile, [d][row]
    __shared__ float cl[DIM * PAD];   // c tile, [d][col]
    __shared__ float xsq[MT];
    __shared__ int   sidx[MT];

    const float* __restrict__ csq = ws_ro + WS_CSQ;
    const float* __restrict__ cwT = ws_ro + WS_CWT;

    const int t    = threadIdx.x;
    const int tx   = t & 15;          // col-quad
    const int ty   = t >> 4;          // row-quad (also d-lane during tile loads)
    const int row0 = blockIdx.x * MT;
    const int b    = row0 >> 12;
    const int hw0  = row0 & (HWSZ - 1);
    const float* __restrict__ xbase = in + (size_t)b * (DIM * HWSZ) + hw0;

    // ---- stage x tile: xl[d][r] = in[b][d][hw0+r] (coalesced float4 per 16-lane group)
    #pragma unroll
    for (int p = 0; p < 4; ++p) {
        int d = p * 16 + ty;
        float4 v = *(const float4*)(xbase + (size_t)d * HWSZ + tx * 4);
        *(float4*)(xl + d * PAD + tx * 4) = v;
    }
    __syncthreads();
    if (t < MT) {                     // per-row ||x||^2 (lanes read consecutive rows: conflict-free)
        float s = 0.f;
        for (int d = 0; d < DIM; ++d) { float xv = xl[d * PAD + t]; s = fmaf(xv, xv, s); }
        xsq[t] = s;
    }

    float best[4]; int bk[4];
    #pragma unroll
    for (int i = 0; i < 4; ++i) { best[i] = INFINITY; bk[i] = 0; }

    for (int kt = 0; kt < KCW / MT; ++kt) {           // 8 codeword tiles of 64
        __syncthreads();                              // xl/xsq ready (kt=0) or prev compute done
        #pragma unroll
        for (int p = 0; p < 4; ++p) {                 // stage c tile from pre-transposed cwT
            int d = p * 16 + ty;
            float4 v = *(const float4*)(cwT + d * KCW + kt * MT + tx * 4);
            *(float4*)(cl + d * PAD + tx * 4) = v;
        }
        __syncthreads();

        float acc[4][4];
        #pragma unroll
        for (int i = 0; i < 4; ++i)
            #pragma unroll
            for (int j = 0; j < 4; ++j) acc[i][j] = 0.f;

        #pragma unroll 8
        for (int d = 0; d < DIM; ++d) {
            float4 xa = *(const float4*)(xl + d * PAD + ty * 4);  // broadcast within 16-lane groups
            float4 cb = *(const float4*)(cl + d * PAD + tx * 4);  // 256B contiguous across 16 lanes
            float xr[4] = {xa.x, xa.y, xa.z, xa.w};
            float cc[4] = {cb.x, cb.y, cb.z, cb.w};
            #pragma unroll
            for (int i = 0; i < 4; ++i)
                #pragma unroll
                for (int j = 0; j < 4; ++j)
                    acc[i][j] = fmaf(xr[i], cc[j], acc[i][j]);
        }

        float4 cs4 = *(const float4*)(csq + kt * MT + tx * 4);
        float csr[4] = {cs4.x, cs4.y, cs4.z, cs4.w};
        #pragma unroll
        for (int i = 0; i < 4; ++i) {
            float xs = xsq[ty * 4 + i];
            #pragma unroll
            for (int j = 0; j < 4; ++j) {
                int k = kt * MT + tx * 4 + j;         // ascending over kt and j
                float dist = (xs + csr[j]) - 2.f * acc[i][j];  // reference rounding order
                if (dist < best[i]) { best[i] = dist; bk[i] = k; }  // strict <: first index wins
            }
        }
    }

    // cross-lane argmin over the 16 col-threads (same wave); ties -> lower k
    #pragma unroll
    for (int off = 1; off < 16; off <<= 1) {
        #pragma unroll
        for (int i = 0; i < 4; ++i) {
            float ob = __shfl_xor(best[i], off, 64);
            int   ok = __shfl_xor(bk[i],  off, 64);
            if (ob < best[i] || (ob == best[i] && ok < bk[i])) { best[i] = ob; bk[i] = ok; }
        }
    }
    if (tx == 0) {
        #pragma unroll
        for (int i = 0; i < 4; ++i) {
            int r = ty * 4 + i;
            sidx[r] = bk[i];
            out[(size_t)NROW * DIM + row0 + r] = (float)bk[i];   // indices chunk
        }
    }
    __syncthreads();

    // gather winning codewords, write quantized (NCHW) + loss partials.
    // seg = t>>6 is wave-uniform: each wave covers one 16-dim segment of all 64 rows;
    // a row's 4 x float4 gather loads live in one 64B line; stores are lane-coalesced.
    const int gr  = t & 63;
    const int seg = t >> 6;
    const int kwin = sidx[gr];
    const float* __restrict__ qp = cw + (size_t)kwin * DIM + seg * 16;
    float* __restrict__ obase = out + (size_t)b * (DIM * HWSZ) + hw0 + gr;
    float lsum = 0.f;
    #pragma unroll
    for (int dd = 0; dd < 4; ++dd) {
        float4 q4 = *(const float4*)(qp + dd * 4);
        float qv[4] = {q4.x, q4.y, q4.z, q4.w};
        #pragma unroll
        for (int c = 0; c < 4; ++c) {
            int d = seg * 16 + dd * 4 + c;
            float xv = xl[d * PAD + gr];              // lanes = consecutive rows: conflict-free
            obase[(size_t)d * HWSZ] = qv[c];
            float diff = qv[c] - xv;
            lsum = fmaf(diff, diff, lsum);
        }
    }
    #pragma unroll
    for (int off = 32; off; off >>= 1) lsum += __shfl_down(lsum, off, 64);
    if ((t & 63) == 0) atomicAdd(loss_acc, lsum);
}

__global__ void vq_finalize_kernel(const float* __restrict__ ws, float* __restrict__ out) {
    // loss = (1 + 0.25) * mean((q - x)^2) over B*H*W*D elements
    out[(size_t)NROW * DIM + NROW] = 1.25f * ws[0] / (float)((size_t)NROW * DIM);
}

extern "C" void kernel_launch(void* const* d_in, const int* in_sizes, int n_in,
                              void* d_out, int out_size, void* d_ws, size_t ws_size,
                              hipStream_t stream) {
    const float* in = (const float*)d_in[0];
    const float* cw = (const float*)d_in[1];
    float* out = (float*)d_out;
    float* ws  = (float*)d_ws;

    hipLaunchKernelGGL(vq_prep_kernel, dim3(DIM * KCW / 256), dim3(256), 0, stream, cw, ws);
    hipLaunchKernelGGL(vq_main_kernel, dim3(NROW / MT), dim3(256), 0, stream,
                       in, cw, ws, ws, out);
    hipLaunchKernelGGL(vq_finalize_kernel, dim3(1), dim3(1), 0, stream, ws, out);
}